// Round 12
// baseline (347.864 us; speedup 1.0000x reference)
//
#include <hip/hip_runtime.h>
#include <hip/hip_bf16.h>
#include <cstdint>
#include <cstddef>

// Problem constants (match reference setup_inputs)
#define N_NODES 20000
#define N_EDGES 320000
#define DIM_IN  2048
#define DIM_H1  512
#define DIM_H2  128
#define DIM_H3  32
#define NPART   64   // pooled partial buffers
static constexpr float LN_EPS = 1e-5f;

typedef __bf16 bf16x8 __attribute__((ext_vector_type(8)));
typedef __bf16 bf16x2 __attribute__((ext_vector_type(2)));
typedef float f32x4 __attribute__((ext_vector_type(4)));

// global -> LDS 16B async DMA. LDS dest is WAVE-UNIFORM base; HW writes
// lane i at base + i*16B. Global src IS per-lane (m104/m173).
__device__ __forceinline__ void glds16(const void* g, void* l) {
  __builtin_amdgcn_global_load_lds(
      (const __attribute__((address_space(1))) unsigned int*)g,
      (__attribute__((address_space(3))) unsigned int*)l, 16, 0, 0);
}

// ---------------------------------------------------------------------------
__global__ void detect_fmt_kernel(const void* eraw, int* flag) {
  const int2* p = (const int2*)eraw;
  int all0 = 1;
  for (int i = 0; i < 32; ++i) if (p[i].y != 0) all0 = 0;
  *flag = all0;  // 1 => int64 layout
}

// Also counts in-degree (fused former count_kernel).
__global__ void convert_edges_kernel(const void* eraw, const int* __restrict__ flag,
                                     int* __restrict__ src, int* __restrict__ dst,
                                     int* __restrict__ cnt, int E) {
  const int is64 = *flag;
  for (int e = blockIdx.x * blockDim.x + threadIdx.x; e < E; e += gridDim.x * blockDim.x) {
    int s, d;
    if (is64) {
      const long long* p = (const long long*)eraw;
      s = (int)p[e];
      d = (int)p[(size_t)E + e];
    } else {
      const int* p = (const int*)eraw;
      s = p[e];
      d = p[(size_t)E + e];
    }
    src[e] = s;
    dst[e] = d;
    atomicAdd(&cnt[d], 1);
  }
}

// Exclusive prefix sum of cnt -> rowptr + cursor copy + dinv (fused). 1 block.
__global__ __launch_bounds__(1024) void scan_kernel(const int* __restrict__ cnt,
                                                    int* __restrict__ rowptr,
                                                    int* __restrict__ cursor,
                                                    float* __restrict__ dinv, int n) {
  __shared__ int s[1024];
  const int t = threadIdx.x;
  const int chunk = (n + 1023) / 1024;
  const int beg = t * chunk;
  const int end = min(beg + chunk, n);
  int sum = 0;
  for (int i = beg; i < end; ++i) sum += cnt[i];
  s[t] = sum;
  __syncthreads();
  for (int d = 1; d < 1024; d <<= 1) {
    int v = (t >= d) ? s[t - d] : 0;
    __syncthreads();
    s[t] += v;
    __syncthreads();
  }
  int run = s[t] - sum;  // exclusive prefix of this thread's chunk
  for (int i = beg; i < end; ++i) {
    rowptr[i] = run;
    cursor[i] = run;
    run += cnt[i];
    dinv[i] = rsqrtf((float)(cnt[i] + 1));  // +1 self loop
  }
  if (t == 1023) rowptr[n] = s[1023];
}

__global__ void scatter_kernel(const int* __restrict__ src, const int* __restrict__ dst,
                               int* __restrict__ cursor, int* __restrict__ csr_src, int E) {
  for (int e = blockIdx.x * blockDim.x + threadIdx.x; e < E; e += gridDim.x * blockDim.x) {
    int d = dst[e];
    int pos = atomicAdd(&cursor[d], 1);
    csr_src[pos] = src[e];
  }
}

// ---------------------------------------------------------------------------
// x fp32 -> bf16 streaming convert (164MB read + 82MB write ~ 40us; leaves
// x_bf16 L3-resident so gemm1's A-staging is L3-served).
__global__ __launch_bounds__(256) void cvt_bf16_kernel(const float* __restrict__ x,
                                                       __bf16* __restrict__ xb, size_t n8) {
  for (size_t i = blockIdx.x * blockDim.x + threadIdx.x; i < n8;
       i += (size_t)gridDim.x * blockDim.x) {
    const float4* p = (const float4*)(x + i * 8);
    float4 v0 = p[0], v1 = p[1];
    bf16x8 o;
    o[0] = (__bf16)v0.x; o[1] = (__bf16)v0.y; o[2] = (__bf16)v0.z; o[3] = (__bf16)v0.w;
    o[4] = (__bf16)v1.x; o[5] = (__bf16)v1.y; o[6] = (__bf16)v1.z; o[7] = (__bf16)v1.w;
    *(bf16x8*)&xb[i * 8] = o;
  }
}

// ---------------------------------------------------------------------------
// W[K][N] fp32 -> WT[N][K] bf16 (for MFMA B^T operand). K,N multiples of 32.
__global__ __launch_bounds__(256) void transpose_cvt_kernel(const float* __restrict__ W,
                                                            __bf16* __restrict__ WT,
                                                            int K, int N) {
  __shared__ float t[32][33];
  const int kb = blockIdx.x * 32, nb = blockIdx.y * 32;
  const int tx = threadIdx.x & 31, ty = threadIdx.x >> 5;  // ty: 0..7
  #pragma unroll
  for (int i = 0; i < 32; i += 8)
    t[ty + i][tx] = W[(size_t)(kb + ty + i) * N + nb + tx];
  __syncthreads();
  #pragma unroll
  for (int i = 0; i < 32; i += 8)
    WT[(size_t)(nb + ty + i) * K + kb + tx] = (__bf16)t[tx][ty + i];
}

// ---------------------------------------------------------------------------
// R7 sync structure (dbuf, glds, counted vmcnt, raw barriers + sched_barrier,
// both-sides slot swizzle) + R10 XCD co-location (all NCOL col-blocks of an
// M-tile on ONE XCD -> A-panel L2/L3-served; FETCH 330->91MB verified R10).
// R12: gemm1 A is pre-converted bf16 -> staged bytes 1075->642MB (traffic
// model: gemm1 was fabric-BW-bound at ~7.6TB/s effective, R11 post-mortem).
template <int BM, int NCOL, typename AT, typename CT>
__global__ __launch_bounds__(256) void gemm_dbuf_kernel(
    const AT* __restrict__ A, const __bf16* __restrict__ BT,
    CT* __restrict__ C, int M, int N, int K) {
  constexpr int MFR = BM / 32;                    // M-frags per wave
  static_assert(sizeof(AT) == 2 ? (BM % 64 == 0) : (BM % 32 == 0), "staging");
  const int Mtiles = (M + BM - 1) / BM;
  int mtile, cblk;
  if constexpr (NCOL == 1) {
    mtile = blockIdx.x;
    cblk = 0;
  } else {
    const int p = blockIdx.x;
    const int xcd = p & 7, slot = p >> 3;
    cblk = slot & (NCOL - 1);
    mtile = (slot / NCOL) * 8 + xcd;
    if (mtile >= Mtiles) return;  // pad block; exits before any barrier
  }
  __shared__ __align__(16) AT     Asm[2][BM * 32];
  __shared__ __align__(16) __bf16 Bsm[2][128 * 32];
  const int tid = threadIdx.x;
  const int wave = tid >> 6;
  const int lane = tid & 63;
  const int row0 = mtile * BM;
  const int col0 = cblk * 128;
  const int wr = (wave >> 1) * (BM / 2);
  const int wc = (wave & 1) * 64;
  constexpr int NGLDS = (sizeof(AT) == 4 ? BM / 32 : BM / 64) + 2;

  f32x4 acc[MFR][4] = {};

  auto STAGE = [&](int buf, int k0) {
    if constexpr (sizeof(AT) == 4) {
      #pragma unroll
      for (int i = 0; i < BM / 32; ++i) {
        const int rbase = wave * (BM / 4) + i * 8;
        int gr = row0 + rbase + (lane >> 3);
        if (gr >= M) gr = M - 1;
        const int ssrc = (lane & 7) ^ (lane >> 3);
        glds16((const float*)A + (size_t)gr * K + k0 + ssrc * 4, &Asm[buf][rbase * 32]);
      }
    } else {
      #pragma unroll
      for (int i = 0; i < BM / 64; ++i) {
        const int rbase = wave * (BM / 4) + i * 16;
        int gr = row0 + rbase + (lane >> 2);
        if (gr >= M) gr = M - 1;
        const int ssrc = (lane & 3) ^ ((lane >> 3) & 3);
        glds16((const __bf16*)A + (size_t)gr * K + k0 + ssrc * 8, &Asm[buf][rbase * 32]);
      }
    }
    #pragma unroll
    for (int j = 0; j < 2; ++j) {
      const int rbase = wave * 32 + j * 16;
      const int gr = col0 + rbase + (lane >> 2);
      const int ssrc = (lane & 3) ^ ((lane >> 3) & 3);
      glds16(BT + (size_t)gr * K + k0 + ssrc * 8, &Bsm[buf][rbase * 32]);
    }
  };

  const int NT = K / 32;
  STAGE(0, 0);  // prologue

  for (int t = 0; t < NT; ++t) {
    const int cur = t & 1;
    if (t + 1 < NT) {
      STAGE(cur ^ 1, (t + 1) * 32);
      asm volatile("s_waitcnt vmcnt(%0)" :: "i"(NGLDS) : "memory");
    } else {
      asm volatile("s_waitcnt vmcnt(0)" ::: "memory");
    }
    __builtin_amdgcn_s_barrier();          // cur buffer collectively visible
    __builtin_amdgcn_sched_barrier(0);     // no hoisting of reads above

    const int q = lane >> 4;
    bf16x8 af[MFR], bfr[4];
    #pragma unroll
    for (int m = 0; m < MFR; ++m) {
      const int row = wr + m * 16 + (lane & 15);
      if constexpr (sizeof(AT) == 4) {
        const int sw = row & 7;
        f32x4 lo = *(const f32x4*)&((const float*)&Asm[cur][0])[row * 32 + (((2 * q) ^ sw) * 4)];
        f32x4 hi = *(const f32x4*)&((const float*)&Asm[cur][0])[row * 32 + (((2 * q + 1) ^ sw) * 4)];
        bf16x8 o;
        o[0] = (__bf16)lo[0]; o[1] = (__bf16)lo[1]; o[2] = (__bf16)lo[2]; o[3] = (__bf16)lo[3];
        o[4] = (__bf16)hi[0]; o[5] = (__bf16)hi[1]; o[6] = (__bf16)hi[2]; o[7] = (__bf16)hi[3];
        af[m] = o;
      } else {
        const int sw = (row >> 1) & 3;
        af[m] = *(const bf16x8*)&((const __bf16*)&Asm[cur][0])[row * 32 + ((q ^ sw) * 8)];
      }
    }
    #pragma unroll
    for (int n = 0; n < 4; ++n) {
      const int row = wc + n * 16 + (lane & 15);
      const int sw = (row >> 1) & 3;
      bfr[n] = *(const bf16x8*)&Bsm[cur][row * 32 + ((q ^ sw) * 8)];
    }
    #pragma unroll
    for (int m = 0; m < MFR; ++m)
      #pragma unroll
      for (int n = 0; n < 4; ++n)
        acc[m][n] = __builtin_amdgcn_mfma_f32_16x16x32_bf16(af[m], bfr[n], acc[m][n], 0, 0, 0);

    __builtin_amdgcn_sched_barrier(0);
    __builtin_amdgcn_s_barrier();          // cur buffer free for restage
  }

  // Epilogue: D layout col=lane&15, row=(lane>>4)*4+j (m89-verified)
  #pragma unroll
  for (int m = 0; m < MFR; ++m) {
    const int r = row0 + wr + m * 16 + (lane >> 4) * 4;
    #pragma unroll
    for (int n = 0; n < 4; ++n) {
      const int c = col0 + wc + n * 16 + (lane & 15);
      #pragma unroll
      for (int j = 0; j < 4; ++j)
        if (r + j < M) C[(size_t)(r + j) * N + c] = (CT)acc[m][n][j];
    }
  }
}

// ---------------------------------------------------------------------------
// Fused GCN aggregate + bias + LayerNorm + ReLU (fp32 xw input).
template <int F, int TPB, typename OutT>
__global__ __launch_bounds__(TPB) void gcn_agg_ln_relu_kernel(
    const float* __restrict__ xw, const float* __restrict__ dinv,
    const int* __restrict__ rowptr, const int* __restrict__ csr_src,
    const float* __restrict__ bias, const float* __restrict__ gamma,
    const float* __restrict__ beta, OutT* __restrict__ h) {
  constexpr int NF = (F + TPB - 1) / TPB;
  const int i = blockIdx.x;
  const int tid = threadIdx.x;
  const float di = dinv[i];
  float acc[NF];
  #pragma unroll
  for (int q = 0; q < NF; ++q) {
    int f = tid + q * TPB;
    acc[q] = (f < F) ? di * xw[(size_t)i * F + f] : 0.f;  // self loop
  }
  const int beg = rowptr[i], end = rowptr[i + 1];
  for (int j = beg; j < end; ++j) {
    int s = csr_src[j];
    float c = dinv[s];
    const float* row = xw + (size_t)s * F;
    #pragma unroll
    for (int q = 0; q < NF; ++q) {
      int f = tid + q * TPB;
      if (f < F) acc[q] += c * row[f];
    }
  }
  float sum = 0.f, sumsq = 0.f;
  #pragma unroll
  for (int q = 0; q < NF; ++q) {
    int f = tid + q * TPB;
    if (f < F) {
      float v = di * acc[q] + bias[f];
      acc[q] = v;
      sum += v;
      sumsq += v * v;
    }
  }
  #pragma unroll
  for (int m = 32; m >= 1; m >>= 1) {
    sum += __shfl_xor(sum, m);
    sumsq += __shfl_xor(sumsq, m);
  }
  constexpr int NW = TPB / 64;
  __shared__ float red[2][NW];
  const int wid = tid >> 6, lane = tid & 63;
  if (lane == 0) { red[0][wid] = sum; red[1][wid] = sumsq; }
  __syncthreads();
  if (tid == 0) {
    float a = 0.f, b2 = 0.f;
    for (int w = 0; w < NW; ++w) { a += red[0][w]; b2 += red[1][w]; }
    red[0][0] = a;
    red[1][0] = b2;
  }
  __syncthreads();
  const float mu = red[0][0] / F;
  const float var = red[1][0] / F - mu * mu;
  const float rstd = rsqrtf(var + LN_EPS);
  #pragma unroll
  for (int q = 0; q < NF; ++q) {
    int f = tid + q * TPB;
    if (f < F) h[(size_t)i * F + f] = (OutT)fmaxf(0.f, (acc[q] - mu) * rstd * gamma[f] + beta[f]);
  }
}

// bf16-input variant, neighbor loop UNROLLED x4 with dual accumulators.
template <int F, int TPB, typename OutT>
__global__ __launch_bounds__(TPB) void gcn_agg_ln_relu_bf16_kernel(
    const __bf16* __restrict__ xw, const float* __restrict__ dinv,
    const int* __restrict__ rowptr, const int* __restrict__ csr_src,
    const float* __restrict__ bias, const float* __restrict__ gamma,
    const float* __restrict__ beta, OutT* __restrict__ h) {
  static_assert(F == 2 * TPB, "layout");
  const int i = blockIdx.x;
  const int tid = threadIdx.x;
  const int f0 = tid * 2;
  const float di = dinv[i];
  bf16x2 v = *(const bf16x2*)&xw[(size_t)i * F + f0];
  float a0 = di * (float)v[0];
  float a1 = di * (float)v[1];
  float b0 = 0.f, b1 = 0.f;
  const int beg = rowptr[i], end = rowptr[i + 1];
  int j = beg;
  for (; j + 3 < end; j += 4) {
    int s0 = csr_src[j], s1 = csr_src[j + 1], s2 = csr_src[j + 2], s3 = csr_src[j + 3];
    float c0 = dinv[s0], c1 = dinv[s1], c2 = dinv[s2], c3 = dinv[s3];
    bf16x2 r0 = *(const bf16x2*)&xw[(size_t)s0 * F + f0];
    bf16x2 r1 = *(const bf16x2*)&xw[(size_t)s1 * F + f0];
    bf16x2 r2 = *(const bf16x2*)&xw[(size_t)s2 * F + f0];
    bf16x2 r3 = *(const bf16x2*)&xw[(size_t)s3 * F + f0];
    a0 += c0 * (float)r0[0]; a1 += c0 * (float)r0[1];
    b0 += c1 * (float)r1[0]; b1 += c1 * (float)r1[1];
    a0 += c2 * (float)r2[0]; a1 += c2 * (float)r2[1];
    b0 += c3 * (float)r3[0]; b1 += c3 * (float)r3[1];
  }
  for (; j < end; ++j) {
    int s = csr_src[j];
    float c = dinv[s];
    bf16x2 r = *(const bf16x2*)&xw[(size_t)s * F + f0];
    a0 += c * (float)r[0];
    a1 += c * (float)r[1];
  }
  a0 += b0;
  a1 += b1;
  a0 = di * a0 + bias[f0];
  a1 = di * a1 + bias[f0 + 1];
  float sum = a0 + a1;
  float sumsq = a0 * a0 + a1 * a1;
  #pragma unroll
  for (int m = 32; m >= 1; m >>= 1) {
    sum += __shfl_xor(sum, m);
    sumsq += __shfl_xor(sumsq, m);
  }
  constexpr int NW = TPB / 64;
  __shared__ float red[2][NW];
  const int wid = tid >> 6, lane = tid & 63;
  if (lane == 0) { red[0][wid] = sum; red[1][wid] = sumsq; }
  __syncthreads();
  if (tid == 0) {
    float a = 0.f, b2 = 0.f;
    for (int w = 0; w < NW; ++w) { a += red[0][w]; b2 += red[1][w]; }
    red[0][0] = a;
    red[1][0] = b2;
  }
  __syncthreads();
  const float mu = red[0][0] / F;
  const float var = red[1][0] / F - mu * mu;
  const float rstd = rsqrtf(var + LN_EPS);
  float o0 = fmaxf(0.f, (a0 - mu) * rstd * gamma[f0] + beta[f0]);
  float o1 = fmaxf(0.f, (a1 - mu) * rstd * gamma[f0 + 1] + beta[f0 + 1]);
  if constexpr (sizeof(OutT) == 2) {
    bf16x2 o; o[0] = (__bf16)o0; o[1] = (__bf16)o1;
    *(bf16x2*)&((__bf16*)h)[(size_t)i * F + f0] = o;
  } else {
    float2 o = make_float2(o0, o1);
    *(float2*)&((float*)h)[(size_t)i * F + f0] = o;
  }
}

// ---------------------------------------------------------------------------
// fp32 tiled GEMM (kept for the tiny GEMM3 / GAT-GEMM). 256 threads.
template <int BM, int BN, int BK, int TM, int TN>
__global__ __launch_bounds__((BM / TM) * (BN / TN)) void sgemm_kernel(
    const float* __restrict__ A, const float* __restrict__ B, float* __restrict__ C,
    int M, int N, int K) {
  constexpr int THREADS = (BM / TM) * (BN / TN);
  __shared__ float As[BK][BM + 4];
  __shared__ float Bs[BK][BN];
  const int tid = threadIdx.x;
  const int tcol = tid % (BN / TN);
  const int trow = tid / (BN / TN);
  const int row0 = blockIdx.y * BM;
  const int col0 = blockIdx.x * BN;
  float acc[TM][TN] = {};
  for (int k0 = 0; k0 < K; k0 += BK) {
    constexpr int A4 = BM * BK / 4;
    #pragma unroll
    for (int i = tid; i < A4; i += THREADS) {
      int r = i / (BK / 4);
      int c4 = i % (BK / 4);
      int gr = row0 + r;
      float4 v = make_float4(0.f, 0.f, 0.f, 0.f);
      if (gr < M) v = *(const float4*)(A + (size_t)gr * K + k0 + c4 * 4);
      As[c4 * 4 + 0][r] = v.x;
      As[c4 * 4 + 1][r] = v.y;
      As[c4 * 4 + 2][r] = v.z;
      As[c4 * 4 + 3][r] = v.w;
    }
    constexpr int B4 = BK * BN / 4;
    #pragma unroll
    for (int i = tid; i < B4; i += THREADS) {
      int r = i / (BN / 4);
      int c4 = i % (BN / 4);
      float4 v = *(const float4*)(B + (size_t)(k0 + r) * N + col0 + c4 * 4);
      *(float4*)(&Bs[r][c4 * 4]) = v;
    }
    __syncthreads();
    #pragma unroll
    for (int kk = 0; kk < BK; ++kk) {
      float ra[TM], rb[TN];
      #pragma unroll
      for (int i = 0; i < TM; ++i) ra[i] = As[kk][trow * TM + i];
      #pragma unroll
      for (int j = 0; j < TN; ++j) rb[j] = Bs[kk][tcol * TN + j];
      #pragma unroll
      for (int i = 0; i < TM; ++i)
        #pragma unroll
        for (int j = 0; j < TN; ++j) acc[i][j] = fmaf(ra[i], rb[j], acc[i][j]);
    }
    __syncthreads();
  }
  #pragma unroll
  for (int i = 0; i < TM; ++i) {
    int gr = row0 + trow * TM + i;
    if (gr >= M) continue;
    #pragma unroll
    for (int j = 0; j < TN; ++j) {
      int gc = col0 + tcol * TN + j;
      if (gc < N) C[(size_t)gr * N + gc] = acc[i][j];
    }
  }
}

// ---------------------------------------------------------------------------
// GAT: per-node attention scores s_src, s_dst (dot with att vectors)
__global__ void gat_sdots_kernel(const float* __restrict__ xwg,
                                 const float* __restrict__ att_src,
                                 const float* __restrict__ att_dst,
                                 float* __restrict__ s_src, float* __restrict__ s_dst, int n) {
  int gid = blockIdx.x * blockDim.x + threadIdx.x;
  int node = gid >> 5;
  int l = threadIdx.x & 31;
  if (node >= n) return;
  float v = xwg[(size_t)node * 32 + l];
  float vs = v * att_src[l];
  float vd = v * att_dst[l];
  #pragma unroll
  for (int m = 16; m >= 1; m >>= 1) {
    vs += __shfl_xor(vs, m);
    vd += __shfl_xor(vd, m);
  }
  if (l == 0) { s_src[node] = vs; s_dst[node] = vd; }
}

__device__ __forceinline__ float leaky02(float x) { return x > 0.f ? x : 0.2f * x; }

// GAT online-softmax aggregate, 128 threads = 4 edge groups (grp = tid>>5).
__global__ __launch_bounds__(128) void gat_agg_kernel(
    const float* __restrict__ xwg, const float* __restrict__ s_src,
    const float* __restrict__ s_dst, const int* __restrict__ rowptr,
    const int* __restrict__ csr_src, const float* __restrict__ bg,
    float* __restrict__ pooled_part) {
  const int i = blockIdx.x;
  const int t = threadIdx.x;
  const int f = t & 31;
  const int grp = t >> 5;  // 0..3
  const float sd = s_dst[i];
  float m, den, acc;
  if (grp == 0) {
    m = leaky02(s_src[i] + sd);
    den = 1.f;
    acc = xwg[(size_t)i * 32 + f];
  } else {
    m = -3.0e38f;
    den = 0.f;
    acc = 0.f;
  }
  const int beg = rowptr[i], end = rowptr[i + 1];
  for (int j = beg + grp; j < end; j += 4) {
    int s = csr_src[j];
    float a = leaky02(s_src[s] + sd);
    float mn = fmaxf(m, a);
    float sc = __expf(m - mn);
    float ea = __expf(a - mn);
    acc = acc * sc + ea * xwg[(size_t)s * 32 + f];
    den = den * sc + ea;
    m = mn;
  }
  {
    float m_o = __shfl_xor(m, 32);
    float den_o = __shfl_xor(den, 32);
    float acc_o = __shfl_xor(acc, 32);
    float mn = fmaxf(m, m_o);
    float sc = __expf(m - mn);
    float so = __expf(m_o - mn);
    den = den * sc + den_o * so;
    acc = acc * sc + acc_o * so;
    m = mn;
  }
  __shared__ float smem[3][32];
  if (t >= 64 && t < 96) { smem[0][f] = m; smem[1][f] = den; smem[2][f] = acc; }
  __syncthreads();
  if (t < 32) {
    float m_o = smem[0][f], den_o = smem[1][f], acc_o = smem[2][f];
    float mn = fmaxf(m, m_o);
    float sc = __expf(m - mn);
    float so = __expf(m_o - mn);
    float den_t = den * sc + den_o * so;
    float acc_t = acc * sc + acc_o * so;
    float out = fmaxf(acc_t / den_t + bg[f], 0.f);
    atomicAdd(&pooled_part[(size_t)(i & (NPART - 1)) * 32 + f], out);
  }
}

__global__ __launch_bounds__(64) void final_fc_kernel(const float* __restrict__ pooled_part,
                                                      const float* __restrict__ fc_w,
                                                      const float* __restrict__ fc_b,
                                                      float* __restrict__ out, float invN) {
  const int lane = threadIdx.x;
  const int f = lane & 31, half = lane >> 5;
  float p = 0.f;
  #pragma unroll
  for (int b = 0; b < NPART / 2; ++b)
    p += pooled_part[(size_t)(half * (NPART / 2) + b) * 32 + f];
  p += __shfl_xor(p, 32);
  p *= invN;
  #pragma unroll
  for (int c = 0; c < 2; ++c) {
    float v = (lane < 32) ? p * fc_w[f * 2 + c] : 0.f;
    #pragma unroll
    for (int m = 16; m >= 1; m >>= 1) v += __shfl_xor(v, m);
    if (lane == 0) out[c] = v + fc_b[c];
  }
}

// ---------------------------------------------------------------------------
extern "C" void kernel_launch(void* const* d_in, const int* in_sizes, int n_in,
                              void* d_out, int out_size, void* d_ws, size_t ws_size,
                              hipStream_t stream) {
  const float* x       = (const float*)d_in[0];
  const void*  edges   = d_in[1];
  const float* W1      = (const float*)d_in[2];
  const float* b1      = (const float*)d_in[3];
  const float* ln1_g   = (const float*)d_in[4];
  const float* ln1_b   = (const float*)d_in[5];
  const float* W2      = (const float*)d_in[6];
  const float* b2      = (const float*)d_in[7];
  const float* ln2_g   = (const float*)d_in[8];
  const float* ln2_b   = (const float*)d_in[9];
  const float* W3      = (const float*)d_in[10];
  const float* b3      = (const float*)d_in[11];
  const float* ln3_g   = (const float*)d_in[12];
  const float* ln3_b   = (const float*)d_in[13];
  const float* Wg      = (const float*)d_in[14];
  const float* att_src = (const float*)d_in[15];
  const float* att_dst = (const float*)d_in[16];
  const float* bg      = (const float*)d_in[17];
  const float* fc_w    = (const float*)d_in[18];
  const float* fc_b    = (const float*)d_in[19];
  float* out = (float*)d_out;

  const int N = N_NODES, E = N_EDGES;

  // workspace layout
  char* ws = (char*)d_ws;
  size_t off = 0;
  auto alloc = [&](size_t bytes) {
    size_t o = off;
    off = (off + bytes + 255) & ~(size_t)255;
    return o;
  };
  size_t o_xb     = alloc((size_t)N * DIM_IN * 2);   // x in bf16 (82 MB)
  size_t o_bufA   = alloc((size_t)N * DIM_H1 * 4);
  size_t o_bufB   = alloc((size_t)N * DIM_H1 * 4);
  size_t o_w1t    = alloc((size_t)DIM_IN * DIM_H1 * 2);
  size_t o_w2t    = alloc((size_t)DIM_H1 * DIM_H2 * 2);
  size_t o_src    = alloc((size_t)E * 4);
  size_t o_dst    = alloc((size_t)E * 4);
  size_t o_csr    = alloc((size_t)E * 4);
  size_t o_cnt    = alloc((size_t)N * 4);
  size_t o_rowptr = alloc((size_t)(N + 1) * 4);
  size_t o_cursor = alloc((size_t)N * 4);
  size_t o_dinv   = alloc((size_t)N * 4);
  size_t o_ssrc   = alloc((size_t)N * 4);
  size_t o_sdst   = alloc((size_t)N * 4);
  size_t o_pooled = alloc((size_t)NPART * 32 * 4);
  size_t o_flag   = alloc(4);

  __bf16* xb    = (__bf16*)(ws + o_xb);
  float* bufA   = (float*)(ws + o_bufA);
  float* bufB   = (float*)(ws + o_bufB);
  __bf16* W1T   = (__bf16*)(ws + o_w1t);
  __bf16* W2T   = (__bf16*)(ws + o_w2t);
  int*   srcI   = (int*)(ws + o_src);
  int*   dstI   = (int*)(ws + o_dst);
  int*   csr    = (int*)(ws + o_csr);
  int*   cnt    = (int*)(ws + o_cnt);
  int*   rowptr = (int*)(ws + o_rowptr);
  int*   cursor = (int*)(ws + o_cursor);
  float* dinv   = (float*)(ws + o_dinv);
  float* ssrc   = (float*)(ws + o_ssrc);
  float* sdst   = (float*)(ws + o_sdst);
  float* pooled = (float*)(ws + o_pooled);
  int*   flag   = (int*)(ws + o_flag);

  hipMemsetAsync(cnt, 0, (size_t)N * 4, stream);
  hipMemsetAsync(pooled, 0, (size_t)NPART * 32 * 4, stream);

  const int EB = (E + 255) / 256;

  // Graph preprocessing (CSR by dst, reused by all 4 conv layers)
  detect_fmt_kernel<<<1, 1, 0, stream>>>(edges, flag);
  convert_edges_kernel<<<EB, 256, 0, stream>>>(edges, flag, srcI, dstI, cnt, E);
  scan_kernel<<<1, 1024, 0, stream>>>(cnt, rowptr, cursor, dinv, N);
  scatter_kernel<<<EB, 256, 0, stream>>>(srcI, dstI, cursor, csr, E);

  // Weight transposes + x fp32->bf16 (leaves xb L3-resident for gemm1)
  transpose_cvt_kernel<<<dim3(DIM_IN / 32, DIM_H1 / 32), 256, 0, stream>>>(W1, W1T, DIM_IN, DIM_H1);
  transpose_cvt_kernel<<<dim3(DIM_H1 / 32, DIM_H2 / 32), 256, 0, stream>>>(W2, W2T, DIM_H1, DIM_H2);
  cvt_bf16_kernel<<<2048, 256, 0, stream>>>(x, xb, (size_t)N * DIM_IN / 8);

  const int MB128 = (N + 127) / 128;  // 157

  // Layer 1: xw1 = xb @ W1 (bf16 A: staged bytes 1075->642MB; BM=128;
  // XCD co-location NCOL=4; grid ceil(157/8)*8*4 = 640)
  gemm_dbuf_kernel<128, 4, __bf16, __bf16>
      <<<((MB128 + 7) / 8) * 8 * 4, 256, 0, stream>>>(xb, W1T, (__bf16*)bufA, N, DIM_H1, DIM_IN);
  gcn_agg_ln_relu_bf16_kernel<DIM_H1, 256, __bf16>
      <<<N, 256, 0, stream>>>((const __bf16*)bufA, dinv, rowptr, csr, b1, ln1_g, ln1_b, (__bf16*)bufB);

  // Layer 2: xw2 = h1(bf16) @ W2 (BM=128, single col-block, bf16 out)
  gemm_dbuf_kernel<128, 1, __bf16, __bf16>
      <<<MB128, 256, 0, stream>>>((const __bf16*)bufB, W2T, (__bf16*)bufA, N, DIM_H2, DIM_H1);
  gcn_agg_ln_relu_bf16_kernel<DIM_H2, 64, float>
      <<<N, 64, 0, stream>>>((const __bf16*)bufA, dinv, rowptr, csr, b2, ln2_g, ln2_b, bufB);

  // Layer 3: xw3 = h2 @ W3 (20000x128x32, tiny -> fp32 sgemm)
  sgemm_kernel<128, 32, 16, 8, 2>
      <<<dim3(1, MB128), 256, 0, stream>>>(bufB, W3, bufA, N, DIM_H3, DIM_H2);
  gcn_agg_ln_relu_kernel<DIM_H3, 64, float>
      <<<N, 64, 0, stream>>>(bufA, dinv, rowptr, csr, b3, ln3_g, ln3_b, bufB);

  // GAT: xwg = h3 @ Wg (20000x32x32)
  sgemm_kernel<128, 32, 16, 8, 2>
      <<<dim3(1, MB128), 256, 0, stream>>>(bufB, Wg, bufA, N, DIM_H3, DIM_H3);
  gat_sdots_kernel<<<(N * 32 + 255) / 256, 256, 0, stream>>>(bufA, att_src, att_dst, ssrc, sdst, N);
  gat_agg_kernel<<<N, 128, 0, stream>>>(bufA, ssrc, sdst, rowptr, csr, bg, pooled);

  final_fc_kernel<<<1, 64, 0, stream>>>(pooled, fc_w, fc_b, out, 1.f / (float)N);
}

// Round 13
// 343.500 us; speedup vs baseline: 1.0127x; 1.0127x over previous
//
#include <hip/hip_runtime.h>
#include <hip/hip_bf16.h>
#include <cstdint>
#include <cstddef>

// Problem constants (match reference setup_inputs)
#define N_NODES 20000
#define N_EDGES 320000
#define DIM_IN  2048
#define DIM_H1  512
#define DIM_H2  128
#define DIM_H3  32
#define NPART   64   // pooled partial buffers
static constexpr float LN_EPS = 1e-5f;

typedef __bf16 bf16x8 __attribute__((ext_vector_type(8)));
typedef __bf16 bf16x2 __attribute__((ext_vector_type(2)));
typedef float f32x4 __attribute__((ext_vector_type(4)));

// global -> LDS 16B async DMA. LDS dest is WAVE-UNIFORM base; HW writes
// lane i at base + i*16B. Global src IS per-lane (m104/m173).
__device__ __forceinline__ void glds16(const void* g, void* l) {
  __builtin_amdgcn_global_load_lds(
      (const __attribute__((address_space(1))) unsigned int*)g,
      (__attribute__((address_space(3))) unsigned int*)l, 16, 0, 0);
}

// ---------------------------------------------------------------------------
__global__ void detect_fmt_kernel(const void* eraw, int* flag) {
  const int2* p = (const int2*)eraw;
  int all0 = 1;
  for (int i = 0; i < 32; ++i) if (p[i].y != 0) all0 = 0;
  *flag = all0;  // 1 => int64 layout
}

// Also counts in-degree (fused former count_kernel).
__global__ void convert_edges_kernel(const void* eraw, const int* __restrict__ flag,
                                     int* __restrict__ src, int* __restrict__ dst,
                                     int* __restrict__ cnt, int E) {
  const int is64 = *flag;
  for (int e = blockIdx.x * blockDim.x + threadIdx.x; e < E; e += gridDim.x * blockDim.x) {
    int s, d;
    if (is64) {
      const long long* p = (const long long*)eraw;
      s = (int)p[e];
      d = (int)p[(size_t)E + e];
    } else {
      const int* p = (const int*)eraw;
      s = p[e];
      d = p[(size_t)E + e];
    }
    src[e] = s;
    dst[e] = d;
    atomicAdd(&cnt[d], 1);
  }
}

// Exclusive prefix sum of cnt -> rowptr + cursor copy + dinv (fused). 1 block.
__global__ __launch_bounds__(1024) void scan_kernel(const int* __restrict__ cnt,
                                                    int* __restrict__ rowptr,
                                                    int* __restrict__ cursor,
                                                    float* __restrict__ dinv, int n) {
  __shared__ int s[1024];
  const int t = threadIdx.x;
  const int chunk = (n + 1023) / 1024;
  const int beg = t * chunk;
  const int end = min(beg + chunk, n);
  int sum = 0;
  for (int i = beg; i < end; ++i) sum += cnt[i];
  s[t] = sum;
  __syncthreads();
  for (int d = 1; d < 1024; d <<= 1) {
    int v = (t >= d) ? s[t - d] : 0;
    __syncthreads();
    s[t] += v;
    __syncthreads();
  }
  int run = s[t] - sum;  // exclusive prefix of this thread's chunk
  for (int i = beg; i < end; ++i) {
    rowptr[i] = run;
    cursor[i] = run;
    run += cnt[i];
    dinv[i] = rsqrtf((float)(cnt[i] + 1));  // +1 self loop
  }
  if (t == 1023) rowptr[n] = s[1023];
}

__global__ void scatter_kernel(const int* __restrict__ src, const int* __restrict__ dst,
                               int* __restrict__ cursor, int* __restrict__ csr_src, int E) {
  for (int e = blockIdx.x * blockDim.x + threadIdx.x; e < E; e += gridDim.x * blockDim.x) {
    int d = dst[e];
    int pos = atomicAdd(&cursor[d], 1);
    csr_src[pos] = src[e];
  }
}

// ---------------------------------------------------------------------------
// x fp32 -> bf16 streaming convert (246MB traffic ~ 40us; leaves xb
// L3-resident so gemm1's A-staging is L2/L3-served).
__global__ __launch_bounds__(256) void cvt_bf16_kernel(const float* __restrict__ x,
                                                       __bf16* __restrict__ xb, size_t n8) {
  for (size_t i = blockIdx.x * blockDim.x + threadIdx.x; i < n8;
       i += (size_t)gridDim.x * blockDim.x) {
    const float4* p = (const float4*)(x + i * 8);
    float4 v0 = p[0], v1 = p[1];
    bf16x8 o;
    o[0] = (__bf16)v0.x; o[1] = (__bf16)v0.y; o[2] = (__bf16)v0.z; o[3] = (__bf16)v0.w;
    o[4] = (__bf16)v1.x; o[5] = (__bf16)v1.y; o[6] = (__bf16)v1.z; o[7] = (__bf16)v1.w;
    *(bf16x8*)&xb[i * 8] = o;
  }
}

// ---------------------------------------------------------------------------
// W[K][N] fp32 -> WT[N][K] bf16 (for MFMA B^T operand). K,N multiples of 32.
__global__ __launch_bounds__(256) void transpose_cvt_kernel(const float* __restrict__ W,
                                                            __bf16* __restrict__ WT,
                                                            int K, int N) {
  __shared__ float t[32][33];
  const int kb = blockIdx.x * 32, nb = blockIdx.y * 32;
  const int tx = threadIdx.x & 31, ty = threadIdx.x >> 5;  // ty: 0..7
  #pragma unroll
  for (int i = 0; i < 32; i += 8)
    t[ty + i][tx] = W[(size_t)(kb + ty + i) * N + nb + tx];
  __syncthreads();
  #pragma unroll
  for (int i = 0; i < 32; i += 8)
    WT[(size_t)(nb + ty + i) * K + kb + tx] = (__bf16)t[tx][ty + i];
}

// ---------------------------------------------------------------------------
// bf16 MFMA GEMM, 3-buffer prefetch-distance-2 (T3/T4 depth 2), XCD
// co-location (R10: FETCH 330->91MB). R13: with bf16 A, 3-buf LDS = 48KB
// = same 2.45 blocks/CU as dbuf (grid-capped) -> clean depth test without
// R8's occupancy confound. Each load gets ~2 compute phases (> L2/L3
// latency). Counted vmcnt per R8 derivation: outstanding tiles {t,t+1,t+2}
// -> wait 2*NGLDS leaves t+1,t+2 in flight, tile t complete.
// Both-sides slot swizzle (rule #21), raw barriers + sched_barrier (#18).
template <int BM, int NCOL, typename CT>
__global__ __launch_bounds__(256) void gemm_3buf_kernel(
    const __bf16* __restrict__ A, const __bf16* __restrict__ BT,
    CT* __restrict__ C, int M, int N, int K) {
  constexpr int MFR = BM / 32;  // M-frags per wave
  static_assert(BM % 64 == 0, "bf16 staging");
  const int Mtiles = (M + BM - 1) / BM;
  int mtile, cblk;
  if constexpr (NCOL == 1) {
    mtile = blockIdx.x;
    cblk = 0;
  } else {
    const int p = blockIdx.x;
    const int xcd = p & 7, slot = p >> 3;
    cblk = slot & (NCOL - 1);
    mtile = (slot / NCOL) * 8 + xcd;
    if (mtile >= Mtiles) return;  // pad block; exits before any barrier
  }
  __shared__ __align__(16) __bf16 Asm[3][BM * 32];
  __shared__ __align__(16) __bf16 Bsm[3][128 * 32];
  const int tid = threadIdx.x;
  const int wave = tid >> 6;
  const int lane = tid & 63;
  const int row0 = mtile * BM;
  const int col0 = cblk * 128;
  const int wr = (wave >> 1) * (BM / 2);
  const int wc = (wave & 1) * 64;
  constexpr int NGLDS = BM / 64 + 2;  // glds issues per wave per stage

  f32x4 acc[MFR][4] = {};

  auto STAGE = [&](int buf, int k0) {
    #pragma unroll
    for (int i = 0; i < BM / 64; ++i) {  // 16 rows per issue
      const int rbase = wave * (BM / 4) + i * 16;
      int gr = row0 + rbase + (lane >> 2);
      if (gr >= M) gr = M - 1;
      const int ssrc = (lane & 3) ^ ((lane >> 3) & 3);
      glds16(A + (size_t)gr * K + k0 + ssrc * 8, &Asm[buf][rbase * 32]);
    }
    #pragma unroll
    for (int j = 0; j < 2; ++j) {
      const int rbase = wave * 32 + j * 16;
      const int gr = col0 + rbase + (lane >> 2);
      const int ssrc = (lane & 3) ^ ((lane >> 3) & 3);
      glds16(BT + (size_t)gr * K + k0 + ssrc * 8, &Bsm[buf][rbase * 32]);
    }
  };

  const int NT = K / 32;
  STAGE(0, 0);
  if (NT > 1) STAGE(1, 32);

  int buf = 0;
  for (int t = 0; t < NT; ++t) {
    if (t + 2 < NT) {
      // overwrites buffer consumed at t-1 (all waves passed its end barrier)
      STAGE((buf + 2) % 3, (t + 2) * 32);
      asm volatile("s_waitcnt vmcnt(%0)" :: "i"(2 * NGLDS) : "memory");
    } else if (t + 1 < NT) {
      asm volatile("s_waitcnt vmcnt(%0)" :: "i"(NGLDS) : "memory");
    } else {
      asm volatile("s_waitcnt vmcnt(0)" ::: "memory");
    }
    __builtin_amdgcn_s_barrier();          // buf collectively visible
    __builtin_amdgcn_sched_barrier(0);     // no hoisting of reads above

    const int q = lane >> 4;
    bf16x8 af[MFR], bfr[4];
    #pragma unroll
    for (int m = 0; m < MFR; ++m) {
      const int row = wr + m * 16 + (lane & 15);
      const int sw = (row >> 1) & 3;
      af[m] = *(const bf16x8*)&Asm[buf][row * 32 + ((q ^ sw) * 8)];
    }
    #pragma unroll
    for (int n = 0; n < 4; ++n) {
      const int row = wc + n * 16 + (lane & 15);
      const int sw = (row >> 1) & 3;
      bfr[n] = *(const bf16x8*)&Bsm[buf][row * 32 + ((q ^ sw) * 8)];
    }
    #pragma unroll
    for (int m = 0; m < MFR; ++m)
      #pragma unroll
      for (int n = 0; n < 4; ++n)
        acc[m][n] = __builtin_amdgcn_mfma_f32_16x16x32_bf16(af[m], bfr[n], acc[m][n], 0, 0, 0);

    __builtin_amdgcn_sched_barrier(0);
    __builtin_amdgcn_s_barrier();          // buf free for restage
    buf = (buf + 1) % 3;
  }

  // Epilogue: D layout col=lane&15, row=(lane>>4)*4+j (m89-verified)
  #pragma unroll
  for (int m = 0; m < MFR; ++m) {
    const int r = row0 + wr + m * 16 + (lane >> 4) * 4;
    #pragma unroll
    for (int n = 0; n < 4; ++n) {
      const int c = col0 + wc + n * 16 + (lane & 15);
      #pragma unroll
      for (int j = 0; j < 4; ++j)
        if (r + j < M) C[(size_t)(r + j) * N + c] = (CT)acc[m][n][j];
    }
  }
}

// ---------------------------------------------------------------------------
// Fused GCN aggregate + bias + LayerNorm + ReLU (fp32 xw input).
template <int F, int TPB, typename OutT>
__global__ __launch_bounds__(TPB) void gcn_agg_ln_relu_kernel(
    const float* __restrict__ xw, const float* __restrict__ dinv,
    const int* __restrict__ rowptr, const int* __restrict__ csr_src,
    const float* __restrict__ bias, const float* __restrict__ gamma,
    const float* __restrict__ beta, OutT* __restrict__ h) {
  constexpr int NF = (F + TPB - 1) / TPB;
  const int i = blockIdx.x;
  const int tid = threadIdx.x;
  const float di = dinv[i];
  float acc[NF];
  #pragma unroll
  for (int q = 0; q < NF; ++q) {
    int f = tid + q * TPB;
    acc[q] = (f < F) ? di * xw[(size_t)i * F + f] : 0.f;  // self loop
  }
  const int beg = rowptr[i], end = rowptr[i + 1];
  for (int j = beg; j < end; ++j) {
    int s = csr_src[j];
    float c = dinv[s];
    const float* row = xw + (size_t)s * F;
    #pragma unroll
    for (int q = 0; q < NF; ++q) {
      int f = tid + q * TPB;
      if (f < F) acc[q] += c * row[f];
    }
  }
  float sum = 0.f, sumsq = 0.f;
  #pragma unroll
  for (int q = 0; q < NF; ++q) {
    int f = tid + q * TPB;
    if (f < F) {
      float v = di * acc[q] + bias[f];
      acc[q] = v;
      sum += v;
      sumsq += v * v;
    }
  }
  #pragma unroll
  for (int m = 32; m >= 1; m >>= 1) {
    sum += __shfl_xor(sum, m);
    sumsq += __shfl_xor(sumsq, m);
  }
  constexpr int NW = TPB / 64;
  __shared__ float red[2][NW];
  const int wid = tid >> 6, lane = tid & 63;
  if (lane == 0) { red[0][wid] = sum; red[1][wid] = sumsq; }
  __syncthreads();
  if (tid == 0) {
    float a = 0.f, b2 = 0.f;
    for (int w = 0; w < NW; ++w) { a += red[0][w]; b2 += red[1][w]; }
    red[0][0] = a;
    red[1][0] = b2;
  }
  __syncthreads();
  const float mu = red[0][0] / F;
  const float var = red[1][0] / F - mu * mu;
  const float rstd = rsqrtf(var + LN_EPS);
  #pragma unroll
  for (int q = 0; q < NF; ++q) {
    int f = tid + q * TPB;
    if (f < F) h[(size_t)i * F + f] = (OutT)fmaxf(0.f, (acc[q] - mu) * rstd * gamma[f] + beta[f]);
  }
}

// bf16-input variant, neighbor loop UNROLLED x4 with dual accumulators.
template <int F, int TPB, typename OutT>
__global__ __launch_bounds__(TPB) void gcn_agg_ln_relu_bf16_kernel(
    const __bf16* __restrict__ xw, const float* __restrict__ dinv,
    const int* __restrict__ rowptr, const int* __restrict__ csr_src,
    const float* __restrict__ bias, const float* __restrict__ gamma,
    const float* __restrict__ beta, OutT* __restrict__ h) {
  static_assert(F == 2 * TPB, "layout");
  const int i = blockIdx.x;
  const int tid = threadIdx.x;
  const int f0 = tid * 2;
  const float di = dinv[i];
  bf16x2 v = *(const bf16x2*)&xw[(size_t)i * F + f0];
  float a0 = di * (float)v[0];
  float a1 = di * (float)v[1];
  float b0 = 0.f, b1 = 0.f;
  const int beg = rowptr[i], end = rowptr[i + 1];
  int j = beg;
  for (; j + 3 < end; j += 4) {
    int s0 = csr_src[j], s1 = csr_src[j + 1], s2 = csr_src[j + 2], s3 = csr_src[j + 3];
    float c0 = dinv[s0], c1 = dinv[s1], c2 = dinv[s2], c3 = dinv[s3];
    bf16x2 r0 = *(const bf16x2*)&xw[(size_t)s0 * F + f0];
    bf16x2 r1 = *(const bf16x2*)&xw[(size_t)s1 * F + f0];
    bf16x2 r2 = *(const bf16x2*)&xw[(size_t)s2 * F + f0];
    bf16x2 r3 = *(const bf16x2*)&xw[(size_t)s3 * F + f0];
    a0 += c0 * (float)r0[0]; a1 += c0 * (float)r0[1];
    b0 += c1 * (float)r1[0]; b1 += c1 * (float)r1[1];
    a0 += c2 * (float)r2[0]; a1 += c2 * (float)r2[1];
    b0 += c3 * (float)r3[0]; b1 += c3 * (float)r3[1];
  }
  for (; j < end; ++j) {
    int s = csr_src[j];
    float c = dinv[s];
    bf16x2 r = *(const bf16x2*)&xw[(size_t)s * F + f0];
    a0 += c * (float)r[0];
    a1 += c * (float)r[1];
  }
  a0 += b0;
  a1 += b1;
  a0 = di * a0 + bias[f0];
  a1 = di * a1 + bias[f0 + 1];
  float sum = a0 + a1;
  float sumsq = a0 * a0 + a1 * a1;
  #pragma unroll
  for (int m = 32; m >= 1; m >>= 1) {
    sum += __shfl_xor(sum, m);
    sumsq += __shfl_xor(sumsq, m);
  }
  constexpr int NW = TPB / 64;
  __shared__ float red[2][NW];
  const int wid = tid >> 6, lane = tid & 63;
  if (lane == 0) { red[0][wid] = sum; red[1][wid] = sumsq; }
  __syncthreads();
  if (tid == 0) {
    float a = 0.f, b2 = 0.f;
    for (int w = 0; w < NW; ++w) { a += red[0][w]; b2 += red[1][w]; }
    red[0][0] = a;
    red[1][0] = b2;
  }
  __syncthreads();
  const float mu = red[0][0] / F;
  const float var = red[1][0] / F - mu * mu;
  const float rstd = rsqrtf(var + LN_EPS);
  float o0 = fmaxf(0.f, (a0 - mu) * rstd * gamma[f0] + beta[f0]);
  float o1 = fmaxf(0.f, (a1 - mu) * rstd * gamma[f0 + 1] + beta[f0 + 1]);
  if constexpr (sizeof(OutT) == 2) {
    bf16x2 o; o[0] = (__bf16)o0; o[1] = (__bf16)o1;
    *(bf16x2*)&((__bf16*)h)[(size_t)i * F + f0] = o;
  } else {
    float2 o = make_float2(o0, o1);
    *(float2*)&((float*)h)[(size_t)i * F + f0] = o;
  }
}

// ---------------------------------------------------------------------------
// fp32 tiled GEMM (kept for the tiny GEMM3 / GAT-GEMM). 256 threads.
template <int BM, int BN, int BK, int TM, int TN>
__global__ __launch_bounds__((BM / TM) * (BN / TN)) void sgemm_kernel(
    const float* __restrict__ A, const float* __restrict__ B, float* __restrict__ C,
    int M, int N, int K) {
  constexpr int THREADS = (BM / TM) * (BN / TN);
  __shared__ float As[BK][BM + 4];
  __shared__ float Bs[BK][BN];
  const int tid = threadIdx.x;
  const int tcol = tid % (BN / TN);
  const int trow = tid / (BN / TN);
  const int row0 = blockIdx.y * BM;
  const int col0 = blockIdx.x * BN;
  float acc[TM][TN] = {};
  for (int k0 = 0; k0 < K; k0 += BK) {
    constexpr int A4 = BM * BK / 4;
    #pragma unroll
    for (int i = tid; i < A4; i += THREADS) {
      int r = i / (BK / 4);
      int c4 = i % (BK / 4);
      int gr = row0 + r;
      float4 v = make_float4(0.f, 0.f, 0.f, 0.f);
      if (gr < M) v = *(const float4*)(A + (size_t)gr * K + k0 + c4 * 4);
      As[c4 * 4 + 0][r] = v.x;
      As[c4 * 4 + 1][r] = v.y;
      As[c4 * 4 + 2][r] = v.z;
      As[c4 * 4 + 3][r] = v.w;
    }
    constexpr int B4 = BK * BN / 4;
    #pragma unroll
    for (int i = tid; i < B4; i += THREADS) {
      int r = i / (BN / 4);
      int c4 = i % (BN / 4);
      float4 v = *(const float4*)(B + (size_t)(k0 + r) * N + col0 + c4 * 4);
      *(float4*)(&Bs[r][c4 * 4]) = v;
    }
    __syncthreads();
    #pragma unroll
    for (int kk = 0; kk < BK; ++kk) {
      float ra[TM], rb[TN];
      #pragma unroll
      for (int i = 0; i < TM; ++i) ra[i] = As[kk][trow * TM + i];
      #pragma unroll
      for (int j = 0; j < TN; ++j) rb[j] = Bs[kk][tcol * TN + j];
      #pragma unroll
      for (int i = 0; i < TM; ++i)
        #pragma unroll
        for (int j = 0; j < TN; ++j) acc[i][j] = fmaf(ra[i], rb[j], acc[i][j]);
    }
    __syncthreads();
  }
  #pragma unroll
  for (int i = 0; i < TM; ++i) {
    int gr = row0 + trow * TM + i;
    if (gr >= M) continue;
    #pragma unroll
    for (int j = 0; j < TN; ++j) {
      int gc = col0 + tcol * TN + j;
      if (gc < N) C[(size_t)gr * N + gc] = acc[i][j];
    }
  }
}

// ---------------------------------------------------------------------------
// GAT: per-node attention scores s_src, s_dst (dot with att vectors)
__global__ void gat_sdots_kernel(const float* __restrict__ xwg,
                                 const float* __restrict__ att_src,
                                 const float* __restrict__ att_dst,
                                 float* __restrict__ s_src, float* __restrict__ s_dst, int n) {
  int gid = blockIdx.x * blockDim.x + threadIdx.x;
  int node = gid >> 5;
  int l = threadIdx.x & 31;
  if (node >= n) return;
  float v = xwg[(size_t)node * 32 + l];
  float vs = v * att_src[l];
  float vd = v * att_dst[l];
  #pragma unroll
  for (int m = 16; m >= 1; m >>= 1) {
    vs += __shfl_xor(vs, m);
    vd += __shfl_xor(vd, m);
  }
  if (l == 0) { s_src[node] = vs; s_dst[node] = vd; }
}

__device__ __forceinline__ float leaky02(float x) { return x > 0.f ? x : 0.2f * x; }

// GAT online-softmax aggregate, 128 threads = 4 edge groups (grp = tid>>5).
__global__ __launch_bounds__(128) void gat_agg_kernel(
    const float* __restrict__ xwg, const float* __restrict__ s_src,
    const float* __restrict__ s_dst, const int* __restrict__ rowptr,
    const int* __restrict__ csr_src, const float* __restrict__ bg,
    float* __restrict__ pooled_part) {
  const int i = blockIdx.x;
  const int t = threadIdx.x;
  const int f = t & 31;
  const int grp = t >> 5;  // 0..3
  const float sd = s_dst[i];
  float m, den, acc;
  if (grp == 0) {
    m = leaky02(s_src[i] + sd);
    den = 1.f;
    acc = xwg[(size_t)i * 32 + f];
  } else {
    m = -3.0e38f;
    den = 0.f;
    acc = 0.f;
  }
  const int beg = rowptr[i], end = rowptr[i + 1];
  for (int j = beg + grp; j < end; j += 4) {
    int s = csr_src[j];
    float a = leaky02(s_src[s] + sd);
    float mn = fmaxf(m, a);
    float sc = __expf(m - mn);
    float ea = __expf(a - mn);
    acc = acc * sc + ea * xwg[(size_t)s * 32 + f];
    den = den * sc + ea;
    m = mn;
  }
  {
    float m_o = __shfl_xor(m, 32);
    float den_o = __shfl_xor(den, 32);
    float acc_o = __shfl_xor(acc, 32);
    float mn = fmaxf(m, m_o);
    float sc = __expf(m - mn);
    float so = __expf(m_o - mn);
    den = den * sc + den_o * so;
    acc = acc * sc + acc_o * so;
    m = mn;
  }
  __shared__ float smem[3][32];
  if (t >= 64 && t < 96) { smem[0][f] = m; smem[1][f] = den; smem[2][f] = acc; }
  __syncthreads();
  if (t < 32) {
    float m_o = smem[0][f], den_o = smem[1][f], acc_o = smem[2][f];
    float mn = fmaxf(m, m_o);
    float sc = __expf(m - mn);
    float so = __expf(m_o - mn);
    float den_t = den * sc + den_o * so;
    float acc_t = acc * sc + acc_o * so;
    float out = fmaxf(acc_t / den_t + bg[f], 0.f);
    atomicAdd(&pooled_part[(size_t)(i & (NPART - 1)) * 32 + f], out);
  }
}

__global__ __launch_bounds__(64) void final_fc_kernel(const float* __restrict__ pooled_part,
                                                      const float* __restrict__ fc_w,
                                                      const float* __restrict__ fc_b,
                                                      float* __restrict__ out, float invN) {
  const int lane = threadIdx.x;
  const int f = lane & 31, half = lane >> 5;
  float p = 0.f;
  #pragma unroll
  for (int b = 0; b < NPART / 2; ++b)
    p += pooled_part[(size_t)(half * (NPART / 2) + b) * 32 + f];
  p += __shfl_xor(p, 32);
  p *= invN;
  #pragma unroll
  for (int c = 0; c < 2; ++c) {
    float v = (lane < 32) ? p * fc_w[f * 2 + c] : 0.f;
    #pragma unroll
    for (int m = 16; m >= 1; m >>= 1) v += __shfl_xor(v, m);
    if (lane == 0) out[c] = v + fc_b[c];
  }
}

// ---------------------------------------------------------------------------
extern "C" void kernel_launch(void* const* d_in, const int* in_sizes, int n_in,
                              void* d_out, int out_size, void* d_ws, size_t ws_size,
                              hipStream_t stream) {
  const float* x       = (const float*)d_in[0];
  const void*  edges   = d_in[1];
  const float* W1      = (const float*)d_in[2];
  const float* b1      = (const float*)d_in[3];
  const float* ln1_g   = (const float*)d_in[4];
  const float* ln1_b   = (const float*)d_in[5];
  const float* W2      = (const float*)d_in[6];
  const float* b2      = (const float*)d_in[7];
  const float* ln2_g   = (const float*)d_in[8];
  const float* ln2_b   = (const float*)d_in[9];
  const float* W3      = (const float*)d_in[10];
  const float* b3      = (const float*)d_in[11];
  const float* ln3_g   = (const float*)d_in[12];
  const float* ln3_b   = (const float*)d_in[13];
  const float* Wg      = (const float*)d_in[14];
  const float* att_src = (const float*)d_in[15];
  const float* att_dst = (const float*)d_in[16];
  const float* bg      = (const float*)d_in[17];
  const float* fc_w    = (const float*)d_in[18];
  const float* fc_b    = (const float*)d_in[19];
  float* out = (float*)d_out;

  const int N = N_NODES, E = N_EDGES;

  // workspace layout
  char* ws = (char*)d_ws;
  size_t off = 0;
  auto alloc = [&](size_t bytes) {
    size_t o = off;
    off = (off + bytes + 255) & ~(size_t)255;
    return o;
  };
  size_t o_xb     = alloc((size_t)N * DIM_IN * 2);   // x in bf16 (82 MB)
  size_t o_bufA   = alloc((size_t)N * DIM_H1 * 4);
  size_t o_bufB   = alloc((size_t)N * DIM_H1 * 4);
  size_t o_w1t    = alloc((size_t)DIM_IN * DIM_H1 * 2);
  size_t o_w2t    = alloc((size_t)DIM_H1 * DIM_H2 * 2);
  size_t o_src    = alloc((size_t)E * 4);
  size_t o_dst    = alloc((size_t)E * 4);
  size_t o_csr    = alloc((size_t)E * 4);
  size_t o_cnt    = alloc((size_t)N * 4);
  size_t o_rowptr = alloc((size_t)(N + 1) * 4);
  size_t o_cursor = alloc((size_t)N * 4);
  size_t o_dinv   = alloc((size_t)N * 4);
  size_t o_ssrc   = alloc((size_t)N * 4);
  size_t o_sdst   = alloc((size_t)N * 4);
  size_t o_pooled = alloc((size_t)NPART * 32 * 4);
  size_t o_flag   = alloc(4);

  __bf16* xb    = (__bf16*)(ws + o_xb);
  float* bufA   = (float*)(ws + o_bufA);
  float* bufB   = (float*)(ws + o_bufB);
  __bf16* W1T   = (__bf16*)(ws + o_w1t);
  __bf16* W2T   = (__bf16*)(ws + o_w2t);
  int*   srcI   = (int*)(ws + o_src);
  int*   dstI   = (int*)(ws + o_dst);
  int*   csr    = (int*)(ws + o_csr);
  int*   cnt    = (int*)(ws + o_cnt);
  int*   rowptr = (int*)(ws + o_rowptr);
  int*   cursor = (int*)(ws + o_cursor);
  float* dinv   = (float*)(ws + o_dinv);
  float* ssrc   = (float*)(ws + o_ssrc);
  float* sdst   = (float*)(ws + o_sdst);
  float* pooled = (float*)(ws + o_pooled);
  int*   flag   = (int*)(ws + o_flag);

  hipMemsetAsync(cnt, 0, (size_t)N * 4, stream);
  hipMemsetAsync(pooled, 0, (size_t)NPART * 32 * 4, stream);

  const int EB = (E + 255) / 256;

  // Graph preprocessing (CSR by dst, reused by all 4 conv layers)
  detect_fmt_kernel<<<1, 1, 0, stream>>>(edges, flag);
  convert_edges_kernel<<<EB, 256, 0, stream>>>(edges, flag, srcI, dstI, cnt, E);
  scan_kernel<<<1, 1024, 0, stream>>>(cnt, rowptr, cursor, dinv, N);
  scatter_kernel<<<EB, 256, 0, stream>>>(srcI, dstI, cursor, csr, E);

  // Weight transposes + x fp32->bf16 (leaves xb L3-resident for gemm1)
  transpose_cvt_kernel<<<dim3(DIM_IN / 32, DIM_H1 / 32), 256, 0, stream>>>(W1, W1T, DIM_IN, DIM_H1);
  transpose_cvt_kernel<<<dim3(DIM_H1 / 32, DIM_H2 / 32), 256, 0, stream>>>(W2, W2T, DIM_H1, DIM_H2);
  cvt_bf16_kernel<<<2048, 256, 0, stream>>>(x, xb, (size_t)N * DIM_IN / 8);

  const int MB128 = (N + 127) / 128;  // 157
  const int MB64  = (N + 63) / 64;    // 313

  // Layer 1: xw1 = xb @ W1 (3-buf depth-2, XCD co-location, bf16 out)
  gemm_3buf_kernel<128, 4, __bf16>
      <<<((MB128 + 7) / 8) * 8 * 4, 256, 0, stream>>>(xb, W1T, (__bf16*)bufA, N, DIM_H1, DIM_IN);
  gcn_agg_ln_relu_bf16_kernel<DIM_H1, 256, __bf16>
      <<<N, 256, 0, stream>>>((const __bf16*)bufA, dinv, rowptr, csr, b1, ln1_g, ln1_b, (__bf16*)bufB);

  // Layer 2: xw2 = h1(bf16) @ W2 (BM=64 -> 313 blocks, 3-buf, bf16 out)
  gemm_3buf_kernel<64, 1, __bf16>
      <<<MB64, 256, 0, stream>>>((const __bf16*)bufB, W2T, (__bf16*)bufA, N, DIM_H2, DIM_H1);
  gcn_agg_ln_relu_bf16_kernel<DIM_H2, 64, float>
      <<<N, 64, 0, stream>>>((const __bf16*)bufA, dinv, rowptr, csr, b2, ln2_g, ln2_b, bufB);

  // Layer 3: xw3 = h2 @ W3 (20000x128x32, tiny -> fp32 sgemm)
  sgemm_kernel<128, 32, 16, 8, 2>
      <<<dim3(1, MB128), 256, 0, stream>>>(bufB, W3, bufA, N, DIM_H3, DIM_H2);
  gcn_agg_ln_relu_kernel<DIM_H3, 64, float>
      <<<N, 64, 0, stream>>>(bufA, dinv, rowptr, csr, b3, ln3_g, ln3_b, bufB);

  // GAT: xwg = h3 @ Wg (20000x32x32)
  sgemm_kernel<128, 32, 16, 8, 2>
      <<<dim3(1, MB128), 256, 0, stream>>>(bufB, Wg, bufA, N, DIM_H3, DIM_H3);
  gat_sdots_kernel<<<(N * 32 + 255) / 256, 256, 0, stream>>>(bufA, att_src, att_dst, ssrc, sdst, N);
  gat_agg_kernel<<<N, 128, 0, stream>>>(bufA, ssrc, sdst, rowptr, csr, bg, pooled);

  final_fc_kernel<<<1, 64, 0, stream>>>(pooled, fc_w, fc_b, out, 1.f / (float)N);
}

// Round 14
// 318.825 us; speedup vs baseline: 1.0911x; 1.0774x over previous
//
#include <hip/hip_runtime.h>
#include <hip/hip_bf16.h>
#include <cstdint>
#include <cstddef>

// Problem constants (match reference setup_inputs)
#define N_NODES 20000
#define N_EDGES 320000
#define DIM_IN  2048
#define DIM_H1  512
#define DIM_H2  128
#define DIM_H3  32
#define NPART   64   // pooled partial buffers
static constexpr float LN_EPS = 1e-5f;

typedef __bf16 bf16x8 __attribute__((ext_vector_type(8)));
typedef __bf16 bf16x2 __attribute__((ext_vector_type(2)));
typedef float f32x4 __attribute__((ext_vector_type(4)));

// global -> LDS 16B async DMA. LDS dest is WAVE-UNIFORM base; HW writes
// lane i at base + i*16B. Global src IS per-lane (m104/m173).
__device__ __forceinline__ void glds16(const void* g, void* l) {
  __builtin_amdgcn_global_load_lds(
      (const __attribute__((address_space(1))) unsigned int*)g,
      (__attribute__((address_space(3))) unsigned int*)l, 16, 0, 0);
}

// ---------------------------------------------------------------------------
__global__ void detect_fmt_kernel(const void* eraw, int* flag) {
  const int2* p = (const int2*)eraw;
  int all0 = 1;
  for (int i = 0; i < 32; ++i) if (p[i].y != 0) all0 = 0;
  *flag = all0;  // 1 => int64 layout
}

// Also counts in-degree (fused former count_kernel).
__global__ void convert_edges_kernel(const void* eraw, const int* __restrict__ flag,
                                     int* __restrict__ src, int* __restrict__ dst,
                                     int* __restrict__ cnt, int E) {
  const int is64 = *flag;
  for (int e = blockIdx.x * blockDim.x + threadIdx.x; e < E; e += gridDim.x * blockDim.x) {
    int s, d;
    if (is64) {
      const long long* p = (const long long*)eraw;
      s = (int)p[e];
      d = (int)p[(size_t)E + e];
    } else {
      const int* p = (const int*)eraw;
      s = p[e];
      d = p[(size_t)E + e];
    }
    src[e] = s;
    dst[e] = d;
    atomicAdd(&cnt[d], 1);
  }
}

// Exclusive prefix sum of cnt -> rowptr + cursor copy + dinv (fused). 1 block.
__global__ __launch_bounds__(1024) void scan_kernel(const int* __restrict__ cnt,
                                                    int* __restrict__ rowptr,
                                                    int* __restrict__ cursor,
                                                    float* __restrict__ dinv, int n) {
  __shared__ int s[1024];
  const int t = threadIdx.x;
  const int chunk = (n + 1023) / 1024;
  const int beg = t * chunk;
  const int end = min(beg + chunk, n);
  int sum = 0;
  for (int i = beg; i < end; ++i) sum += cnt[i];
  s[t] = sum;
  __syncthreads();
  for (int d = 1; d < 1024; d <<= 1) {
    int v = (t >= d) ? s[t - d] : 0;
    __syncthreads();
    s[t] += v;
    __syncthreads();
  }
  int run = s[t] - sum;  // exclusive prefix of this thread's chunk
  for (int i = beg; i < end; ++i) {
    rowptr[i] = run;
    cursor[i] = run;
    run += cnt[i];
    dinv[i] = rsqrtf((float)(cnt[i] + 1));  // +1 self loop
  }
  if (t == 1023) rowptr[n] = s[1023];
}

__global__ void scatter_kernel(const int* __restrict__ src, const int* __restrict__ dst,
                               int* __restrict__ cursor, int* __restrict__ csr_src, int E) {
  for (int e = blockIdx.x * blockDim.x + threadIdx.x; e < E; e += gridDim.x * blockDim.x) {
    int d = dst[e];
    int pos = atomicAdd(&cursor[d], 1);
    csr_src[pos] = src[e];
  }
}

// ---------------------------------------------------------------------------
// W[K][N] fp32 -> WT[N][K] bf16 (for MFMA B^T operand). K,N multiples of 32.
__global__ __launch_bounds__(256) void transpose_cvt_kernel(const float* __restrict__ W,
                                                            __bf16* __restrict__ WT,
                                                            int K, int N) {
  __shared__ float t[32][33];
  const int kb = blockIdx.x * 32, nb = blockIdx.y * 32;
  const int tx = threadIdx.x & 31, ty = threadIdx.x >> 5;  // ty: 0..7
  #pragma unroll
  for (int i = 0; i < 32; i += 8)
    t[ty + i][tx] = W[(size_t)(kb + ty + i) * N + nb + tx];
  __syncthreads();
  #pragma unroll
  for (int i = 0; i < 32; i += 8)
    WT[(size_t)(nb + ty + i) * K + kb + tx] = (__bf16)t[tx][ty + i];
}

// ---------------------------------------------------------------------------
// R11's proven gemm (323us total): dbuf, glds, counted vmcnt, raw barriers +
// sched_barrier(0) (#18), both-sides slot swizzle (#21), fp32-A cvt at read
// (m114), XCD co-location (R10: FETCH 330->91MB).
template <int BM, int NCOL, typename AT, typename CT>
__global__ __launch_bounds__(256) void gemm_dbuf_kernel(
    const AT* __restrict__ A, const __bf16* __restrict__ BT,
    CT* __restrict__ C, int M, int N, int K) {
  constexpr int MFR = BM / 32;                    // M-frags per wave
  static_assert(sizeof(AT) == 2 ? (BM % 64 == 0) : (BM % 32 == 0), "staging");
  const int Mtiles = (M + BM - 1) / BM;
  int mtile, cblk;
  if constexpr (NCOL == 1) {
    mtile = blockIdx.x;
    cblk = 0;
  } else {
    const int p = blockIdx.x;
    const int xcd = p & 7, slot = p >> 3;
    cblk = slot & (NCOL - 1);
    mtile = (slot / NCOL) * 8 + xcd;
    if (mtile >= Mtiles) return;  // pad block; exits before any barrier
  }
  __shared__ __align__(16) AT     Asm[2][BM * 32];
  __shared__ __align__(16) __bf16 Bsm[2][128 * 32];
  const int tid = threadIdx.x;
  const int wave = tid >> 6;
  const int lane = tid & 63;
  const int row0 = mtile * BM;
  const int col0 = cblk * 128;
  const int wr = (wave >> 1) * (BM / 2);
  const int wc = (wave & 1) * 64;
  constexpr int NGLDS = (sizeof(AT) == 4 ? BM / 32 : BM / 64) + 2;

  f32x4 acc[MFR][4] = {};

  auto STAGE = [&](int buf, int k0) {
    if constexpr (sizeof(AT) == 4) {
      #pragma unroll
      for (int i = 0; i < BM / 32; ++i) {
        const int rbase = wave * (BM / 4) + i * 8;
        int gr = row0 + rbase + (lane >> 3);
        if (gr >= M) gr = M - 1;
        const int ssrc = (lane & 7) ^ (lane >> 3);
        glds16((const float*)A + (size_t)gr * K + k0 + ssrc * 4, &Asm[buf][rbase * 32]);
      }
    } else {
      #pragma unroll
      for (int i = 0; i < BM / 64; ++i) {
        const int rbase = wave * (BM / 4) + i * 16;
        int gr = row0 + rbase + (lane >> 2);
        if (gr >= M) gr = M - 1;
        const int ssrc = (lane & 3) ^ ((lane >> 3) & 3);
        glds16((const __bf16*)A + (size_t)gr * K + k0 + ssrc * 8, &Asm[buf][rbase * 32]);
      }
    }
    #pragma unroll
    for (int j = 0; j < 2; ++j) {
      const int rbase = wave * 32 + j * 16;
      const int gr = col0 + rbase + (lane >> 2);
      const int ssrc = (lane & 3) ^ ((lane >> 3) & 3);
      glds16(BT + (size_t)gr * K + k0 + ssrc * 8, &Bsm[buf][rbase * 32]);
    }
  };

  const int NT = K / 32;
  STAGE(0, 0);  // prologue

  for (int t = 0; t < NT; ++t) {
    const int cur = t & 1;
    if (t + 1 < NT) {
      STAGE(cur ^ 1, (t + 1) * 32);
      asm volatile("s_waitcnt vmcnt(%0)" :: "i"(NGLDS) : "memory");
    } else {
      asm volatile("s_waitcnt vmcnt(0)" ::: "memory");
    }
    __builtin_amdgcn_s_barrier();          // cur buffer collectively visible
    __builtin_amdgcn_sched_barrier(0);     // no hoisting of reads above

    const int q = lane >> 4;
    bf16x8 af[MFR], bfr[4];
    #pragma unroll
    for (int m = 0; m < MFR; ++m) {
      const int row = wr + m * 16 + (lane & 15);
      if constexpr (sizeof(AT) == 4) {
        const int sw = row & 7;
        f32x4 lo = *(const f32x4*)&((const float*)&Asm[cur][0])[row * 32 + (((2 * q) ^ sw) * 4)];
        f32x4 hi = *(const f32x4*)&((const float*)&Asm[cur][0])[row * 32 + (((2 * q + 1) ^ sw) * 4)];
        bf16x8 o;
        o[0] = (__bf16)lo[0]; o[1] = (__bf16)lo[1]; o[2] = (__bf16)lo[2]; o[3] = (__bf16)lo[3];
        o[4] = (__bf16)hi[0]; o[5] = (__bf16)hi[1]; o[6] = (__bf16)hi[2]; o[7] = (__bf16)hi[3];
        af[m] = o;
      } else {
        const int sw = (row >> 1) & 3;
        af[m] = *(const bf16x8*)&((const __bf16*)&Asm[cur][0])[row * 32 + ((q ^ sw) * 8)];
      }
    }
    #pragma unroll
    for (int n = 0; n < 4; ++n) {
      const int row = wc + n * 16 + (lane & 15);
      const int sw = (row >> 1) & 3;
      bfr[n] = *(const bf16x8*)&Bsm[cur][row * 32 + ((q ^ sw) * 8)];
    }
    #pragma unroll
    for (int m = 0; m < MFR; ++m)
      #pragma unroll
      for (int n = 0; n < 4; ++n)
        acc[m][n] = __builtin_amdgcn_mfma_f32_16x16x32_bf16(af[m], bfr[n], acc[m][n], 0, 0, 0);

    __builtin_amdgcn_sched_barrier(0);
    __builtin_amdgcn_s_barrier();          // cur buffer free for restage
  }

  // Epilogue: D layout col=lane&15, row=(lane>>4)*4+j (m89-verified)
  #pragma unroll
  for (int m = 0; m < MFR; ++m) {
    const int r = row0 + wr + m * 16 + (lane >> 4) * 4;
    #pragma unroll
    for (int n = 0; n < 4; ++n) {
      const int c = col0 + wc + n * 16 + (lane & 15);
      #pragma unroll
      for (int j = 0; j < 4; ++j)
        if (r + j < M) C[(size_t)(r + j) * N + c] = (CT)acc[m][n][j];
    }
  }
}

// ---------------------------------------------------------------------------
// bf16 3-buffer depth-2 variant (R13's gemm2: BM=64 -> 313 blocks).
template <int BM, typename CT>
__global__ __launch_bounds__(256) void gemm_3buf_kernel(
    const __bf16* __restrict__ A, const __bf16* __restrict__ BT,
    CT* __restrict__ C, int M, int N, int K) {
  constexpr int MFR = BM / 32;
  static_assert(BM % 64 == 0, "bf16 staging");
  const int mtile = blockIdx.x;
  __shared__ __align__(16) __bf16 Asm[3][BM * 32];
  __shared__ __align__(16) __bf16 Bsm[3][128 * 32];
  const int tid = threadIdx.x;
  const int wave = tid >> 6;
  const int lane = tid & 63;
  const int row0 = mtile * BM;
  const int wr = (wave >> 1) * (BM / 2);
  const int wc = (wave & 1) * 64;
  constexpr int NGLDS = BM / 64 + 2;

  f32x4 acc[MFR][4] = {};

  auto STAGE = [&](int buf, int k0) {
    #pragma unroll
    for (int i = 0; i < BM / 64; ++i) {
      const int rbase = wave * (BM / 4) + i * 16;
      int gr = row0 + rbase + (lane >> 2);
      if (gr >= M) gr = M - 1;
      const int ssrc = (lane & 3) ^ ((lane >> 3) & 3);
      glds16(A + (size_t)gr * K + k0 + ssrc * 8, &Asm[buf][rbase * 32]);
    }
    #pragma unroll
    for (int j = 0; j < 2; ++j) {
      const int rbase = wave * 32 + j * 16;
      const int gr = rbase + (lane >> 2);
      const int ssrc = (lane & 3) ^ ((lane >> 3) & 3);
      glds16(BT + (size_t)gr * K + k0 + ssrc * 8, &Bsm[buf][rbase * 32]);
    }
  };

  const int NT = K / 32;
  STAGE(0, 0);
  if (NT > 1) STAGE(1, 32);

  int buf = 0;
  for (int t = 0; t < NT; ++t) {
    if (t + 2 < NT) {
      STAGE((buf + 2) % 3, (t + 2) * 32);
      asm volatile("s_waitcnt vmcnt(%0)" :: "i"(2 * NGLDS) : "memory");
    } else if (t + 1 < NT) {
      asm volatile("s_waitcnt vmcnt(%0)" :: "i"(NGLDS) : "memory");
    } else {
      asm volatile("s_waitcnt vmcnt(0)" ::: "memory");
    }
    __builtin_amdgcn_s_barrier();
    __builtin_amdgcn_sched_barrier(0);

    const int q = lane >> 4;
    bf16x8 af[MFR], bfr[4];
    #pragma unroll
    for (int m = 0; m < MFR; ++m) {
      const int row = wr + m * 16 + (lane & 15);
      const int sw = (row >> 1) & 3;
      af[m] = *(const bf16x8*)&Asm[buf][row * 32 + ((q ^ sw) * 8)];
    }
    #pragma unroll
    for (int n = 0; n < 4; ++n) {
      const int row = wc + n * 16 + (lane & 15);
      const int sw = (row >> 1) & 3;
      bfr[n] = *(const bf16x8*)&Bsm[buf][row * 32 + ((q ^ sw) * 8)];
    }
    #pragma unroll
    for (int m = 0; m < MFR; ++m)
      #pragma unroll
      for (int n = 0; n < 4; ++n)
        acc[m][n] = __builtin_amdgcn_mfma_f32_16x16x32_bf16(af[m], bfr[n], acc[m][n], 0, 0, 0);

    __builtin_amdgcn_sched_barrier(0);
    __builtin_amdgcn_s_barrier();
    buf = (buf + 1) % 3;
  }

  #pragma unroll
  for (int m = 0; m < MFR; ++m) {
    const int r = row0 + wr + m * 16 + (lane >> 4) * 4;
    #pragma unroll
    for (int n = 0; n < 4; ++n) {
      const int c = wc + n * 16 + (lane & 15);
      #pragma unroll
      for (int j = 0; j < 4; ++j)
        if (r + j < M) C[(size_t)(r + j) * N + c] = (CT)acc[m][n][j];
    }
  }
}

// ---------------------------------------------------------------------------
// Fused GCN aggregate + bias + LayerNorm + ReLU (fp32 xw input).
template <int F, int TPB, typename OutT>
__global__ __launch_bounds__(TPB) void gcn_agg_ln_relu_kernel(
    const float* __restrict__ xw, const float* __restrict__ dinv,
    const int* __restrict__ rowptr, const int* __restrict__ csr_src,
    const float* __restrict__ bias, const float* __restrict__ gamma,
    const float* __restrict__ beta, OutT* __restrict__ h) {
  constexpr int NF = (F + TPB - 1) / TPB;
  const int i = blockIdx.x;
  const int tid = threadIdx.x;
  const float di = dinv[i];
  float acc[NF];
  #pragma unroll
  for (int q = 0; q < NF; ++q) {
    int f = tid + q * TPB;
    acc[q] = (f < F) ? di * xw[(size_t)i * F + f] : 0.f;  // self loop
  }
  const int beg = rowptr[i], end = rowptr[i + 1];
  for (int j = beg; j < end; ++j) {
    int s = csr_src[j];
    float c = dinv[s];
    const float* row = xw + (size_t)s * F;
    #pragma unroll
    for (int q = 0; q < NF; ++q) {
      int f = tid + q * TPB;
      if (f < F) acc[q] += c * row[f];
    }
  }
  float sum = 0.f, sumsq = 0.f;
  #pragma unroll
  for (int q = 0; q < NF; ++q) {
    int f = tid + q * TPB;
    if (f < F) {
      float v = di * acc[q] + bias[f];
      acc[q] = v;
      sum += v;
      sumsq += v * v;
    }
  }
  #pragma unroll
  for (int m = 32; m >= 1; m >>= 1) {
    sum += __shfl_xor(sum, m);
    sumsq += __shfl_xor(sumsq, m);
  }
  constexpr int NW = TPB / 64;
  __shared__ float red[2][NW];
  const int wid = tid >> 6, lane = tid & 63;
  if (lane == 0) { red[0][wid] = sum; red[1][wid] = sumsq; }
  __syncthreads();
  if (tid == 0) {
    float a = 0.f, b2 = 0.f;
    for (int w = 0; w < NW; ++w) { a += red[0][w]; b2 += red[1][w]; }
    red[0][0] = a;
    red[1][0] = b2;
  }
  __syncthreads();
  const float mu = red[0][0] / F;
  const float var = red[1][0] / F - mu * mu;
  const float rstd = rsqrtf(var + LN_EPS);
  #pragma unroll
  for (int q = 0; q < NF; ++q) {
    int f = tid + q * TPB;
    if (f < F) h[(size_t)i * F + f] = (OutT)fmaxf(0.f, (acc[q] - mu) * rstd * gamma[f] + beta[f]);
  }
}

// bf16-input variant, neighbor loop UNROLLED x4 with dual accumulators.
template <int F, int TPB, typename OutT>
__global__ __launch_bounds__(TPB) void gcn_agg_ln_relu_bf16_kernel(
    const __bf16* __restrict__ xw, const float* __restrict__ dinv,
    const int* __restrict__ rowptr, const int* __restrict__ csr_src,
    const float* __restrict__ bias, const float* __restrict__ gamma,
    const float* __restrict__ beta, OutT* __restrict__ h) {
  static_assert(F == 2 * TPB, "layout");
  const int i = blockIdx.x;
  const int tid = threadIdx.x;
  const int f0 = tid * 2;
  const float di = dinv[i];
  bf16x2 v = *(const bf16x2*)&xw[(size_t)i * F + f0];
  float a0 = di * (float)v[0];
  float a1 = di * (float)v[1];
  float b0 = 0.f, b1 = 0.f;
  const int beg = rowptr[i], end = rowptr[i + 1];
  int j = beg;
  for (; j + 3 < end; j += 4) {
    int s0 = csr_src[j], s1 = csr_src[j + 1], s2 = csr_src[j + 2], s3 = csr_src[j + 3];
    float c0 = dinv[s0], c1 = dinv[s1], c2 = dinv[s2], c3 = dinv[s3];
    bf16x2 r0 = *(const bf16x2*)&xw[(size_t)s0 * F + f0];
    bf16x2 r1 = *(const bf16x2*)&xw[(size_t)s1 * F + f0];
    bf16x2 r2 = *(const bf16x2*)&xw[(size_t)s2 * F + f0];
    bf16x2 r3 = *(const bf16x2*)&xw[(size_t)s3 * F + f0];
    a0 += c0 * (float)r0[0]; a1 += c0 * (float)r0[1];
    b0 += c1 * (float)r1[0]; b1 += c1 * (float)r1[1];
    a0 += c2 * (float)r2[0]; a1 += c2 * (float)r2[1];
    b0 += c3 * (float)r3[0]; b1 += c3 * (float)r3[1];
  }
  for (; j < end; ++j) {
    int s = csr_src[j];
    float c = dinv[s];
    bf16x2 r = *(const bf16x2*)&xw[(size_t)s * F + f0];
    a0 += c * (float)r[0];
    a1 += c * (float)r[1];
  }
  a0 += b0;
  a1 += b1;
  a0 = di * a0 + bias[f0];
  a1 = di * a1 + bias[f0 + 1];
  float sum = a0 + a1;
  float sumsq = a0 * a0 + a1 * a1;
  #pragma unroll
  for (int m = 32; m >= 1; m >>= 1) {
    sum += __shfl_xor(sum, m);
    sumsq += __shfl_xor(sumsq, m);
  }
  constexpr int NW = TPB / 64;
  __shared__ float red[2][NW];
  const int wid = tid >> 6, lane = tid & 63;
  if (lane == 0) { red[0][wid] = sum; red[1][wid] = sumsq; }
  __syncthreads();
  if (tid == 0) {
    float a = 0.f, b2 = 0.f;
    for (int w = 0; w < NW; ++w) { a += red[0][w]; b2 += red[1][w]; }
    red[0][0] = a;
    red[1][0] = b2;
  }
  __syncthreads();
  const float mu = red[0][0] / F;
  const float var = red[1][0] / F - mu * mu;
  const float rstd = rsqrtf(var + LN_EPS);
  float o0 = fmaxf(0.f, (a0 - mu) * rstd * gamma[f0] + beta[f0]);
  float o1 = fmaxf(0.f, (a1 - mu) * rstd * gamma[f0 + 1] + beta[f0 + 1]);
  if constexpr (sizeof(OutT) == 2) {
    bf16x2 o; o[0] = (__bf16)o0; o[1] = (__bf16)o1;
    *(bf16x2*)&((__bf16*)h)[(size_t)i * F + f0] = o;
  } else {
    float2 o = make_float2(o0, o1);
    *(float2*)&((float*)h)[(size_t)i * F + f0] = o;
  }
}

// ---------------------------------------------------------------------------
// fp32 tiled GEMM (kept for the tiny GEMM3 / GAT-GEMM). 256 threads.
template <int BM, int BN, int BK, int TM, int TN>
__global__ __launch_bounds__((BM / TM) * (BN / TN)) void sgemm_kernel(
    const float* __restrict__ A, const float* __restrict__ B, float* __restrict__ C,
    int M, int N, int K) {
  constexpr int THREADS = (BM / TM) * (BN / TN);
  __shared__ float As[BK][BM + 4];
  __shared__ float Bs[BK][BN];
  const int tid = threadIdx.x;
  const int tcol = tid % (BN / TN);
  const int trow = tid / (BN / TN);
  const int row0 = blockIdx.y * BM;
  const int col0 = blockIdx.x * BN;
  float acc[TM][TN] = {};
  for (int k0 = 0; k0 < K; k0 += BK) {
    constexpr int A4 = BM * BK / 4;
    #pragma unroll
    for (int i = tid; i < A4; i += THREADS) {
      int r = i / (BK / 4);
      int c4 = i % (BK / 4);
      int gr = row0 + r;
      float4 v = make_float4(0.f, 0.f, 0.f, 0.f);
      if (gr < M) v = *(const float4*)(A + (size_t)gr * K + k0 + c4 * 4);
      As[c4 * 4 + 0][r] = v.x;
      As[c4 * 4 + 1][r] = v.y;
      As[c4 * 4 + 2][r] = v.z;
      As[c4 * 4 + 3][r] = v.w;
    }
    constexpr int B4 = BK * BN / 4;
    #pragma unroll
    for (int i = tid; i < B4; i += THREADS) {
      int r = i / (BN / 4);
      int c4 = i % (BN / 4);
      float4 v = *(const float4*)(B + (size_t)(k0 + r) * N + col0 + c4 * 4);
      *(float4*)(&Bs[r][c4 * 4]) = v;
    }
    __syncthreads();
    #pragma unroll
    for (int kk = 0; kk < BK; ++kk) {
      float ra[TM], rb[TN];
      #pragma unroll
      for (int i = 0; i < TM; ++i) ra[i] = As[kk][trow * TM + i];
      #pragma unroll
      for (int j = 0; j < TN; ++j) rb[j] = Bs[kk][tcol * TN + j];
      #pragma unroll
      for (int i = 0; i < TM; ++i)
        #pragma unroll
        for (int j = 0; j < TN; ++j) acc[i][j] = fmaf(ra[i], rb[j], acc[i][j]);
    }
    __syncthreads();
  }
  #pragma unroll
  for (int i = 0; i < TM; ++i) {
    int gr = row0 + trow * TM + i;
    if (gr >= M) continue;
    #pragma unroll
    for (int j = 0; j < TN; ++j) {
      int gc = col0 + tcol * TN + j;
      if (gc < N) C[(size_t)gr * N + gc] = acc[i][j];
    }
  }
}

// ---------------------------------------------------------------------------
// GAT: per-node attention scores s_src, s_dst (dot with att vectors)
__global__ void gat_sdots_kernel(const float* __restrict__ xwg,
                                 const float* __restrict__ att_src,
                                 const float* __restrict__ att_dst,
                                 float* __restrict__ s_src, float* __restrict__ s_dst, int n) {
  int gid = blockIdx.x * blockDim.x + threadIdx.x;
  int node = gid >> 5;
  int l = threadIdx.x & 31;
  if (node >= n) return;
  float v = xwg[(size_t)node * 32 + l];
  float vs = v * att_src[l];
  float vd = v * att_dst[l];
  #pragma unroll
  for (int m = 16; m >= 1; m >>= 1) {
    vs += __shfl_xor(vs, m);
    vd += __shfl_xor(vd, m);
  }
  if (l == 0) { s_src[node] = vs; s_dst[node] = vd; }
}

__device__ __forceinline__ float leaky02(float x) { return x > 0.f ? x : 0.2f * x; }

// GAT online-softmax aggregate, 128 threads = 4 edge groups (grp = tid>>5).
__global__ __launch_bounds__(128) void gat_agg_kernel(
    const float* __restrict__ xwg, const float* __restrict__ s_src,
    const float* __restrict__ s_dst, const int* __restrict__ rowptr,
    const int* __restrict__ csr_src, const float* __restrict__ bg,
    float* __restrict__ pooled_part) {
  const int i = blockIdx.x;
  const int t = threadIdx.x;
  const int f = t & 31;
  const int grp = t >> 5;  // 0..3
  const float sd = s_dst[i];
  float m, den, acc;
  if (grp == 0) {
    m = leaky02(s_src[i] + sd);
    den = 1.f;
    acc = xwg[(size_t)i * 32 + f];
  } else {
    m = -3.0e38f;
    den = 0.f;
    acc = 0.f;
  }
  const int beg = rowptr[i], end = rowptr[i + 1];
  for (int j = beg + grp; j < end; j += 4) {
    int s = csr_src[j];
    float a = leaky02(s_src[s] + sd);
    float mn = fmaxf(m, a);
    float sc = __expf(m - mn);
    float ea = __expf(a - mn);
    acc = acc * sc + ea * xwg[(size_t)s * 32 + f];
    den = den * sc + ea;
    m = mn;
  }
  {
    float m_o = __shfl_xor(m, 32);
    float den_o = __shfl_xor(den, 32);
    float acc_o = __shfl_xor(acc, 32);
    float mn = fmaxf(m, m_o);
    float sc = __expf(m - mn);
    float so = __expf(m_o - mn);
    den = den * sc + den_o * so;
    acc = acc * sc + acc_o * so;
    m = mn;
  }
  __shared__ float smem[3][32];
  if (t >= 64 && t < 96) { smem[0][f] = m; smem[1][f] = den; smem[2][f] = acc; }
  __syncthreads();
  if (t < 32) {
    float m_o = smem[0][f], den_o = smem[1][f], acc_o = smem[2][f];
    float mn = fmaxf(m, m_o);
    float sc = __expf(m - mn);
    float so = __expf(m_o - mn);
    float den_t = den * sc + den_o * so;
    float acc_t = acc * sc + acc_o * so;
    float out = fmaxf(acc_t / den_t + bg[f], 0.f);
    atomicAdd(&pooled_part[(size_t)(i & (NPART - 1)) * 32 + f], out);
  }
}

__global__ __launch_bounds__(64) void final_fc_kernel(const float* __restrict__ pooled_part,
                                                      const float* __restrict__ fc_w,
                                                      const float* __restrict__ fc_b,
                                                      float* __restrict__ out, float invN) {
  const int lane = threadIdx.x;
  const int f = lane & 31, half = lane >> 5;
  float p = 0.f;
  #pragma unroll
  for (int b = 0; b < NPART / 2; ++b)
    p += pooled_part[(size_t)(half * (NPART / 2) + b) * 32 + f];
  p += __shfl_xor(p, 32);
  p *= invN;
  #pragma unroll
  for (int c = 0; c < 2; ++c) {
    float v = (lane < 32) ? p * fc_w[f * 2 + c] : 0.f;
    #pragma unroll
    for (int m = 16; m >= 1; m >>= 1) v += __shfl_xor(v, m);
    if (lane == 0) out[c] = v + fc_b[c];
  }
}

// ---------------------------------------------------------------------------
extern "C" void kernel_launch(void* const* d_in, const int* in_sizes, int n_in,
                              void* d_out, int out_size, void* d_ws, size_t ws_size,
                              hipStream_t stream) {
  const float* x       = (const float*)d_in[0];
  const void*  edges   = d_in[1];
  const float* W1      = (const float*)d_in[2];
  const float* b1      = (const float*)d_in[3];
  const float* ln1_g   = (const float*)d_in[4];
  const float* ln1_b   = (const float*)d_in[5];
  const float* W2      = (const float*)d_in[6];
  const float* b2      = (const float*)d_in[7];
  const float* ln2_g   = (const float*)d_in[8];
  const float* ln2_b   = (const float*)d_in[9];
  const float* W3      = (const float*)d_in[10];
  const float* b3      = (const float*)d_in[11];
  const float* ln3_g   = (const float*)d_in[12];
  const float* ln3_b   = (const float*)d_in[13];
  const float* Wg      = (const float*)d_in[14];
  const float* att_src = (const float*)d_in[15];
  const float* att_dst = (const float*)d_in[16];
  const float* bg      = (const float*)d_in[17];
  const float* fc_w    = (const float*)d_in[18];
  const float* fc_b    = (const float*)d_in[19];
  float* out = (float*)d_out;

  const int N = N_NODES, E = N_EDGES;

  // workspace layout
  char* ws = (char*)d_ws;
  size_t off = 0;
  auto alloc = [&](size_t bytes) {
    size_t o = off;
    off = (off + bytes + 255) & ~(size_t)255;
    return o;
  };
  size_t o_bufA   = alloc((size_t)N * DIM_H1 * 4);
  size_t o_bufB   = alloc((size_t)N * DIM_H1 * 4);
  size_t o_w1t    = alloc((size_t)DIM_IN * DIM_H1 * 2);
  size_t o_w2t    = alloc((size_t)DIM_H1 * DIM_H2 * 2);
  size_t o_src    = alloc((size_t)E * 4);
  size_t o_dst    = alloc((size_t)E * 4);
  size_t o_csr    = alloc((size_t)E * 4);
  size_t o_cnt    = alloc((size_t)N * 4);
  size_t o_rowptr = alloc((size_t)(N + 1) * 4);
  size_t o_cursor = alloc((size_t)N * 4);
  size_t o_dinv   = alloc((size_t)N * 4);
  size_t o_ssrc   = alloc((size_t)N * 4);
  size_t o_sdst   = alloc((size_t)N * 4);
  size_t o_pooled = alloc((size_t)NPART * 32 * 4);
  size_t o_flag   = alloc(4);

  float* bufA   = (float*)(ws + o_bufA);
  float* bufB   = (float*)(ws + o_bufB);
  __bf16* W1T   = (__bf16*)(ws + o_w1t);
  __bf16* W2T   = (__bf16*)(ws + o_w2t);
  int*   srcI   = (int*)(ws + o_src);
  int*   dstI   = (int*)(ws + o_dst);
  int*   csr    = (int*)(ws + o_csr);
  int*   cnt    = (int*)(ws + o_cnt);
  int*   rowptr = (int*)(ws + o_rowptr);
  int*   cursor = (int*)(ws + o_cursor);
  float* dinv   = (float*)(ws + o_dinv);
  float* ssrc   = (float*)(ws + o_ssrc);
  float* sdst   = (float*)(ws + o_sdst);
  float* pooled = (float*)(ws + o_pooled);
  int*   flag   = (int*)(ws + o_flag);

  hipMemsetAsync(cnt, 0, (size_t)N * 4, stream);
  hipMemsetAsync(pooled, 0, (size_t)NPART * 32 * 4, stream);

  const int EB = (E + 255) / 256;

  // Graph preprocessing (CSR by dst, reused by all 4 conv layers)
  detect_fmt_kernel<<<1, 1, 0, stream>>>(edges, flag);
  convert_edges_kernel<<<EB, 256, 0, stream>>>(edges, flag, srcI, dstI, cnt, E);
  scan_kernel<<<1, 1024, 0, stream>>>(cnt, rowptr, cursor, dinv, N);
  scatter_kernel<<<EB, 256, 0, stream>>>(srcI, dstI, cursor, csr, E);

  // Weight transposes (bf16 B^T operands for the MFMA GEMMs)
  transpose_cvt_kernel<<<dim3(DIM_IN / 32, DIM_H1 / 32), 256, 0, stream>>>(W1, W1T, DIM_IN, DIM_H1);
  transpose_cvt_kernel<<<dim3(DIM_H1 / 32, DIM_H2 / 32), 256, 0, stream>>>(W2, W2T, DIM_H1, DIM_H2);

  const int MB128 = (N + 127) / 128;  // 157
  const int MB96  = (N + 95) / 96;    // 209
  const int MB64  = (N + 63) / 64;    // 313

  // Layer 1: xw1 = x @ W1 (R11 config: fp32-A, BM=96, NCOL=4 XCD co-location)
  gemm_dbuf_kernel<96, 4, float, __bf16>
      <<<((MB96 + 7) / 8) * 8 * 4, 256, 0, stream>>>(x, W1T, (__bf16*)bufA, N, DIM_H1, DIM_IN);
  gcn_agg_ln_relu_bf16_kernel<DIM_H1, 256, __bf16>
      <<<N, 256, 0, stream>>>((const __bf16*)bufA, dinv, rowptr, csr, b1, ln1_g, ln1_b, (__bf16*)bufB);

  // Layer 2: xw2 = h1(bf16) @ W2 (R13 config: BM=64, 3-buf depth-2)
  gemm_3buf_kernel<64, __bf16>
      <<<MB64, 256, 0, stream>>>((const __bf16*)bufB, W2T, (__bf16*)bufA, N, DIM_H2, DIM_H1);
  gcn_agg_ln_relu_bf16_kernel<DIM_H2, 64, float>
      <<<N, 64, 0, stream>>>((const __bf16*)bufA, dinv, rowptr, csr, b2, ln2_g, ln2_b, bufB);

  // Layer 3: xw3 = h2 @ W3 (20000x128x32, tiny -> fp32 sgemm)
  sgemm_kernel<128, 32, 16, 8, 2>
      <<<dim3(1, MB128), 256, 0, stream>>>(bufB, W3, bufA, N, DIM_H3, DIM_H2);
  gcn_agg_ln_relu_kernel<DIM_H3, 64, float>
      <<<N, 64, 0, stream>>>(bufA, dinv, rowptr, csr, b3, ln3_g, ln3_b, bufB);

  // GAT: xwg = h3 @ Wg (20000x32x32)
  sgemm_kernel<128, 32, 16, 8, 2>
      <<<dim3(1, MB128), 256, 0, stream>>>(bufB, Wg, bufA, N, DIM_H3, DIM_H3);
  gat_sdots_kernel<<<(N * 32 + 255) / 256, 256, 0, stream>>>(bufA, att_src, att_dst, ssrc, sdst, N);
  gat_agg_kernel<<<N, 128, 0, stream>>>(bufA, ssrc, sdst, rowptr, csr, bg, pooled);

  final_fc_kernel<<<1, 64, 0, stream>>>(pooled, fc_w, fc_b, out, 1.f / (float)N);
}